// Round 11
// baseline (448.204 us; speedup 1.0000x reference)
//
#include <hip/hip_runtime.h>
#include <hip/hip_cooperative_groups.h>
#include <cstdint>
#include <cstddef>

namespace cg = cooperative_groups;

// Problem dims
#define B_ROWS 65536
#define D_IN   784
#define KP     800      // D_IN padded to multiple of 32
#define D_H    300
#define NP     320      // D_H padded to multiple of 64
#define D_OUT  10
#define NP2    16       // D_OUT padded to 16
#define EPS    1e-5f
#define NBLK   1024     // blocks in gemm1 and tail grids

typedef _Float16 half8  __attribute__((ext_vector_type(8)));
typedef float    floatx4 __attribute__((ext_vector_type(4)));

// Workspace layout (bytes). part[] aliases the old oc region: part is
// consumed by k_stat1 BEFORE k_tail writes part2 (distinct offset).
#define OFF_S1   ((size_t)0)                       // _Float16[320*800]   = 512000
#define OFF_H    ((size_t)512000)                  // _Float16[65536*320] = 41943040
#define OFF_ZB   (OFF_H + (size_t)41943040)        // float[16] zero block
#define OFF_W2   (OFF_ZB + (size_t)2560)           // _Float16[16*320]    = 10240
#define OFF_ST2  (OFF_W2 + (size_t)10240)          // float[32]
#define OFF_OC   (OFF_ST2 + (size_t)256)           // scratch region (part alias)
#define OFF_P1   OFF_OC                            // float[640][1024]
#define OFF_P2   (OFF_OC + (size_t)4194304)        // float[32][1024]     = 131072

// ---------------- K0: binarize W1 -> fp16 (+-1), zero-padded to [320][800]
// Also zeroes the 64B pad-source block used by k_gemm1's tail DMA redirect.
__global__ void k_prep1(const float* __restrict__ W1, _Float16* __restrict__ S1,
                        float* __restrict__ zb)
{
    if (blockIdx.x == 0 && threadIdx.x < 16) zb[threadIdx.x] = 0.0f;
    int idx = blockIdx.x * 256 + threadIdx.x;      // 0..255999
    int n = idx / KP;
    int k = idx - n * KP;
    float v = 0.0f;
    if (n < D_H && k < D_IN)
        v = (W1[n * D_IN + k] >= 0.0f) ? 1.0f : -1.0f;
    S1[idx] = (_Float16)v;
}

// ---------------- K1: h = x @ S1^T  (M=65536, N=320, K=800), fp16 MFMA
// R8 EXACT (wall-confirmed twice: 91.3 / 91.8 us). GLOBAL_LOAD_LDS staging:
// A-tile [64][32] fp32 DMA'd straight to LDS; 2x 16B global_load_lds per
// thread issued at the TOP of step s for step s+1's buffer; end-of-step
// barrier uses COUNTED s_waitcnt vmcnt(5) (drains only the 2 DMA loads,
// leaves the 5 B-prefetch loads in flight). fp32->fp16 cvt on the
// fragment-read side. Rule-21 both-sides XOR swizzle (residual 8-way
// conflict is pigeonhole-forced at 128B row stride; ~128cy/step = 7%,
// not worth attacking). K-pad tail redirects to a zeroed block.
// LEDGER (R1-R10): direct-A loads, counted-vmcnt depth 2 AND 3, BK=64,
// 2x occupancy, fine phase-split+setprio, B single-buffer -- all
// profiled-null or worse. Do not re-litigate without new counter evidence.

typedef const __attribute__((address_space(1))) void* gas_p;
typedef __attribute__((address_space(3))) void* las_p;

__device__ __forceinline__ void gload_lds16(const float* g, float* l)
{
    __builtin_amdgcn_global_load_lds((gas_p)g, (las_p)l, 16, 0, 0);
}

#define PF_B(BV, NK)                                                        \
    _Pragma("unroll")                                                       \
    for (int nt = 0; nt < 5; ++nt)                                          \
        BV[nt] = *(const half8*)(bb + (size_t)nt * 16 * KP + (NK));

#define ISSUE_A(BUF, KK)                                                    \
    gload_lds16(gA0 + (KK), &Afl[BUF][0][0] + lof);                         \
    gload_lds16(gA1 + (KK), &Afl[BUF][0][0] + 1024 + lof);

#define ISSUE_A_TAIL(BUF)                                                   \
    gload_lds16(ts0, &Afl[BUF][0][0] + lof);                                \
    gload_lds16(ts1, &Afl[BUF][0][0] + 1024 + lof);

// read swizzled chunks ce=(2q)^e, co=ce^1 of row mt*16+row15, cvt to half8
#define AFRAGF(BUF)                                                         \
    _Pragma("unroll")                                                       \
    for (int mt = 0; mt < 4; ++mt) {                                        \
        floatx4 f0 = *(const floatx4*)&Afl[BUF][mt * 16 + row15][ce * 4];   \
        floatx4 f1 = *(const floatx4*)&Afl[BUF][mt * 16 + row15][co * 4];   \
        half8 hv;                                                           \
        _Pragma("unroll")                                                   \
        for (int j = 0; j < 4; ++j) {                                       \
            hv[j]     = (_Float16)f0[j];                                    \
            hv[4 + j] = (_Float16)f1[j];                                    \
        }                                                                   \
        a[mt] = hv;                                                         \
    }

#define COMPUTE(BV)                                                         \
    _Pragma("unroll")                                                       \
    for (int nt = 0; nt < 5; ++nt)                                          \
        _Pragma("unroll")                                                   \
        for (int mt = 0; mt < 4; ++mt)                                      \
            acc[mt][nt] = __builtin_amdgcn_mfma_f32_16x16x32_f16(           \
                a[mt], BV[nt], acc[mt][nt], 0, 0, 0);

// counted drain: waits the 2 A-DMA loads (oldest), leaves 5 B loads in
// flight across the barrier. sched_barrier(0) pins issue order (rule 18).
#define STEP_SYNC()                                                         \
    __builtin_amdgcn_sched_barrier(0);                                      \
    asm volatile("s_waitcnt vmcnt(5)" ::: "memory");                        \
    __builtin_amdgcn_sched_barrier(0);                                      \
    __builtin_amdgcn_s_barrier();                                           \
    __builtin_amdgcn_sched_barrier(0);

__global__ __launch_bounds__(256) void k_gemm1(const float* __restrict__ x,
                                               const _Float16* __restrict__ S1,
                                               _Float16* __restrict__ h,
                                               float* __restrict__ part,
                                               const float* __restrict__ zb)
{
    __shared__ __align__(16) float Afl[2][64][32];   // 2 x 8 KB
    const int t     = threadIdx.x;
    const int wave  = t >> 6;
    const int lane  = t & 63;
    const int row15 = lane & 15;
    const int quad  = lane >> 4;
    const int m0    = blockIdx.x * 64;

    // DMA staging: slot = wave*64+lane (call0) / +256 (call1); row = slot>>3,
    // storage chunk = slot&7, source chunk = (slot&7)^(row&7).
    const int rA   = wave * 8 + (lane >> 3);          // call0 row (call1: +32)
    const int cswz = (lane & 7) ^ ((lane >> 3) & 7);  // swizzled source chunk
    const int lof  = wave * 256;                      // LDS float offset, call0
    const float* gA0 = x + (size_t)(m0 + rA) * D_IN + cswz * 4;
    const float* gA1 = gA0 + (size_t)32 * D_IN;
    // tail step (kk=768): cols 768+cswz*4 >= 784 for cswz>=4 -> zero block
    const float* ts0 = (cswz >= 4) ? zb : (gA0 + 768);
    const float* ts1 = (cswz >= 4) ? zb : (gA1 + 768);

    // fragment-read swizzle (e = row15&7 since (mt*16)&7 == 0)
    const int ce = (2 * quad) ^ (row15 & 7);
    const int co = ce ^ 1;

    // B fragment base (MFMA B layout: lane holds col=row15, k=quad*8..+8)
    const _Float16* bb = S1 + (size_t)(wave * 80 + row15) * KP + quad * 8;

    floatx4 acc[4][5] = {};
    half8   b0[5], b1[5];
    half8   a[4];

    // prologue: DMA A(0)->buf0; b0 <- B(0); counted drain; barrier
    ISSUE_A(0, 0)
    __builtin_amdgcn_sched_barrier(0);
    PF_B(b0, 0)
    STEP_SYNC()

    for (int i = 0; i < 12; ++i) {
        const int kk = i * 64;
        // even step s=2i: computes buf0/b0; DMA A(s+1)->buf1; prefetch b1
        ISSUE_A(1, kk + 32)
        __builtin_amdgcn_sched_barrier(0);
        PF_B(b1, kk + 32)
        AFRAGF(0)
        COMPUTE(b0)
        STEP_SYNC()
        // odd step s=2i+1: computes buf1/b1; DMA A(s+2)->buf0; prefetch b0
        if (i < 11) { ISSUE_A(0, kk + 64) } else { ISSUE_A_TAIL(0) }
        __builtin_amdgcn_sched_barrier(0);
        PF_B(b0, kk + 64)              // i=11 -> B(24) at koff 768
        AFRAGF(1)
        COMPUTE(b1)
        STEP_SYNC()
    }
    // tail step 24: buf0/b0 (k = 768..799; pad cols are zeros both sides)
    AFRAGF(0)
    COMPUTE(b0)

    // --- epilogue: store h (C/D layout: col=lane&15, row=quad*4+r) + stats
    float s[5] = {}, q[5] = {};
#pragma unroll
    for (int mt = 0; mt < 4; ++mt)
#pragma unroll
        for (int nt = 0; nt < 5; ++nt)
#pragma unroll
            for (int r = 0; r < 4; ++r) {
                float v = acc[mt][nt][r];
                int m = m0 + mt * 16 + quad * 4 + r;
                int n = wave * 80 + nt * 16 + row15;
                h[(size_t)m * NP + n] = (_Float16)v;
                s[nt] += v;
                q[nt] += v * v;
            }
    // reduce over quad (waves own disjoint col ranges -> no cross-wave combine)
#pragma unroll
    for (int nt = 0; nt < 5; ++nt) {
        s[nt] += __shfl_xor(s[nt], 16); s[nt] += __shfl_xor(s[nt], 32);
        q[nt] += __shfl_xor(q[nt], 16); q[nt] += __shfl_xor(q[nt], 32);
    }
    if (quad == 0) {
#pragma unroll
        for (int nt = 0; nt < 5; ++nt) {
            int col = wave * 80 + nt * 16 + row15;
            part[(size_t)col * NBLK + blockIdx.x]        = s[nt];
            part[(size_t)(NP + col) * NBLK + blockIdx.x] = q[nt];
        }
    }
}

// ---------------- K2: FUSED reduce + BN1-fold-into-W2
// One block per hidden col j: reduce sum AND sumsq partials, then threads
// 0..15 write the BN1-scaled binarized W2 column.
__global__ void k_stat1(const float* __restrict__ part, const float* __restrict__ gamma1,
                        const float* __restrict__ W2, _Float16* __restrict__ w2h)
{
    __shared__ float redS[4], redQ[4];
    const int j = blockIdx.x;            // 0..319
    const int t = threadIdx.x;           // 256
    const float* ps = part + (size_t)j * NBLK;
    const float* pq = part + (size_t)(NP + j) * NBLK;
    float s = ps[t] + ps[t + 256] + ps[t + 512] + ps[t + 768];
    float q = pq[t] + pq[t + 256] + pq[t + 512] + pq[t + 768];
#pragma unroll
    for (int off = 1; off < 64; off <<= 1) {
        s += __shfl_xor(s, off);
        q += __shfl_xor(q, off);
    }
    if ((t & 63) == 0) { redS[t >> 6] = s; redQ[t >> 6] = q; }
    __syncthreads();
    if (t < NP2) {
        float S = redS[0] + redS[1] + redS[2] + redS[3];
        float Q = redQ[0] + redQ[1] + redQ[2] + redQ[3];
        float mean = S * (1.0f / 65536.0f);
        float var  = Q * (1.0f / 65536.0f) - mean * mean;
        float a1   = 0.0f;
        if (j < D_H) a1 = gamma1[j] / sqrtf(var + EPS);
        float w = 0.0f;
        if (t < D_OUT && j < D_H)
            w = (W2[t * D_H + j] >= 0.0f) ? a1 : -a1;
        w2h[t * NP + j] = (_Float16)w;
    }
}

// ---------------- K3 (COOPERATIVE): fused gemm2 + stat2 + BN2 epilogue.
// Each block computes its 64x16 oc tile and KEEPS IT IN REGISTERS (4 VGPR/
// lane), writes per-block stat partials, grid.sync(), blocks 0..15 reduce
// to (mean, scale), grid.sync(), all blocks apply BN2 from registers and
// write out directly. Eliminates the oc global round-trip (8.4 MB) and two
// dispatch bubbles. w2h (10 KB, L2-hot) is read directly from global (no
// LDS staging barrier). Co-residency: 1024 blk x 4 waves = 16 waves/CU,
// ~40 VGPR, <1 KB LDS -> 4 blocks/CU fits with margin (bounds cap 128 VGPR).
// Numerics: same MFMA order as old k_gemm2; oc previously stored as exact
// fp32 -> bit-identical output.
__global__ __launch_bounds__(256, 4) void k_tail(
    const _Float16* __restrict__ h, const _Float16* __restrict__ w2h,
    float* __restrict__ part2, float* __restrict__ st2,
    const float* __restrict__ gamma2, const float* __restrict__ beta2,
    float* __restrict__ out)
{
    __shared__ float reds[4][16], redq[4][16];
    __shared__ float redS[4], redQ[4];
    const int t     = threadIdx.x;
    const int wave  = t >> 6;
    const int lane  = t & 63;
    const int row15 = lane & 15;
    const int quad  = lane >> 4;
    const int m0    = blockIdx.x * 64 + wave * 16;

    // --- phase 1: oc tile in registers + stat partials
    const _Float16* hp = h   + (size_t)(m0 + row15) * NP + quad * 8;
    const _Float16* wp = w2h + (size_t)row15 * NP + quad * 8;
    floatx4 acc = {};
#pragma unroll
    for (int kk = 0; kk < NP; kk += 32) {
        half8 a2 = *(const half8*)(hp + kk);
        half8 b2 = *(const half8*)(wp + kk);
        acc = __builtin_amdgcn_mfma_f32_16x16x32_f16(a2, b2, acc, 0, 0, 0);
    }
    float s = 0.f, q = 0.f;
#pragma unroll
    for (int r = 0; r < 4; ++r) { float v = acc[r]; s += v; q += v * v; }
    s += __shfl_xor(s, 16); s += __shfl_xor(s, 32);
    q += __shfl_xor(q, 16); q += __shfl_xor(q, 32);
    if (lane < 16) { reds[wave][row15] = s; redq[wave][row15] = q; }
    __syncthreads();
    if (t < 16) {
        float S = reds[0][t] + reds[1][t] + reds[2][t] + reds[3][t];
        float Q = redq[0][t] + redq[1][t] + redq[2][t] + redq[3][t];
        part2[(size_t)t * NBLK + blockIdx.x]        = S;
        part2[(size_t)(16 + t) * NBLK + blockIdx.x] = Q;
    }
    __threadfence();
    cg::this_grid().sync();

    // --- phase 2: blocks 0..15 reduce partials -> (mean, scale)
    if (blockIdx.x < 16) {
        const int k = blockIdx.x;
        const float* ps = part2 + (size_t)k * NBLK;
        const float* pq = part2 + (size_t)(16 + k) * NBLK;
        float s2 = ps[t] + ps[t + 256] + ps[t + 512] + ps[t + 768];
        float q2 = pq[t] + pq[t + 256] + pq[t + 512] + pq[t + 768];
#pragma unroll
        for (int off = 1; off < 64; off <<= 1) {
            s2 += __shfl_xor(s2, off);
            q2 += __shfl_xor(q2, off);
        }
        if ((t & 63) == 0) { redS[t >> 6] = s2; redQ[t >> 6] = q2; }
        __syncthreads();
        if (t == 0) {
            float S = redS[0] + redS[1] + redS[2] + redS[3];
            float Q = redQ[0] + redQ[1] + redQ[2] + redQ[3];
            float mean = S * (1.0f / 65536.0f);
            float var  = Q * (1.0f / 65536.0f) - mean * mean;
            float sc   = (k < D_OUT) ? gamma2[k] / sqrtf(var + EPS) : 0.0f;
            st2[k]      = mean;
            st2[16 + k] = sc;
        }
    }
    __threadfence();
    cg::this_grid().sync();

    // --- phase 3: BN2 from registers -> out[65536][10]
    float mean = st2[row15];
    float sc   = st2[16 + row15];
    if (row15 < D_OUT) {
        float b = beta2[row15];
#pragma unroll
        for (int r = 0; r < 4; ++r)
            out[(size_t)(m0 + quad * 4 + r) * D_OUT + row15] =
                (acc[r] - mean) * sc + b;
    }
}

extern "C" void kernel_launch(void* const* d_in, const int* in_sizes, int n_in,
                              void* d_out, int out_size, void* d_ws, size_t ws_size,
                              hipStream_t stream)
{
    const float* x      = (const float*)d_in[0];
    const float* W1     = (const float*)d_in[1];
    const float* gamma1 = (const float*)d_in[2];
    // d_in[3] = beta1 : algebraically cancels under BN2's mean subtraction
    const float* W2     = (const float*)d_in[4];
    const float* gamma2 = (const float*)d_in[5];
    const float* beta2  = (const float*)d_in[6];
    float* out = (float*)d_out;

    char* ws = (char*)d_ws;
    _Float16* S1    = (_Float16*)(ws + OFF_S1);
    _Float16* h     = (_Float16*)(ws + OFF_H);
    float*    zb    = (float*)(ws + OFF_ZB);
    _Float16* w2h   = (_Float16*)(ws + OFF_W2);
    float*    st2   = (float*)(ws + OFF_ST2);
    float*    part  = (float*)(ws + OFF_P1);
    float*    part2 = (float*)(ws + OFF_P2);

    k_prep1 <<<1000, 256, 0, stream>>>(W1, S1, zb);
    k_gemm1 <<<NBLK, 256, 0, stream>>>(x, S1, h, part, zb);
    k_stat1 <<<320, 256, 0, stream>>>(part, gamma1, W2, w2h);

    void* args[] = { (void*)&h, (void*)&w2h, (void*)&part2, (void*)&st2,
                     (void*)&gamma2, (void*)&beta2, (void*)&out };
    hipLaunchCooperativeKernel((void*)k_tail, dim3(NBLK), dim3(256),
                               args, 0, stream);
}

// Round 12
// 91.786 us; speedup vs baseline: 4.8831x; 4.8831x over previous
//
#include <hip/hip_runtime.h>
#include <cstdint>
#include <cstddef>

// Problem dims
#define B_ROWS 65536
#define D_IN   784
#define KP     800      // D_IN padded to multiple of 32
#define D_H    300
#define NP     320      // D_H padded to multiple of 64
#define D_OUT  10
#define NP2    16       // D_OUT padded to 16
#define EPS    1e-5f
#define NBLK   1024     // blocks in gemm1 and gemm2 grids

typedef _Float16 half8  __attribute__((ext_vector_type(8)));
typedef float    floatx4 __attribute__((ext_vector_type(4)));

// Workspace layout (bytes). part[] aliases oc[]: part is consumed by k_stat1
// BEFORE k_gemm2 writes oc (strictly ordered on one stream).
#define OFF_S1   ((size_t)0)                       // _Float16[320*800]   = 512000
#define OFF_H    ((size_t)512000)                  // _Float16[65536*320] = 41943040
#define OFF_ZB   (OFF_H + (size_t)41943040)        // float[16] zero block (old ST1 slot)
#define OFF_W2   (OFF_ZB + (size_t)2560)           // _Float16[16*320]    = 10240
#define OFF_ST2  (OFF_W2 + (size_t)10240)          // float[32]
#define OFF_OC   (OFF_ST2 + (size_t)256)           // float[65536*16]     = 4194304
#define OFF_P1   OFF_OC                            // float[640][1024] (alias, time-disjoint)
#define OFF_P2   (OFF_OC + (size_t)4194304)        // float[32][1024]     = 131072

// ---------------- K0: binarize W1 -> fp16 (+-1), zero-padded to [320][800]
// Also zeroes the 64B pad-source block used by k_gemm1's tail DMA redirect.
__global__ void k_prep1(const float* __restrict__ W1, _Float16* __restrict__ S1,
                        float* __restrict__ zb)
{
    if (blockIdx.x == 0 && threadIdx.x < 16) zb[threadIdx.x] = 0.0f;
    int idx = blockIdx.x * 256 + threadIdx.x;      // 0..255999
    int n = idx / KP;
    int k = idx - n * KP;
    float v = 0.0f;
    if (n < D_H && k < D_IN)
        v = (W1[n * D_IN + k] >= 0.0f) ? 1.0f : -1.0f;
    S1[idx] = (_Float16)v;
}

// ---------------- K1: h = x @ S1^T  (M=65536, N=320, K=800), fp16 MFMA
// R8 EXACT (wall-confirmed twice: 91.3 / 91.8 us). GLOBAL_LOAD_LDS staging:
// A-tile [64][32] fp32 DMA'd straight to LDS; 2x 16B global_load_lds per
// thread issued at the TOP of step s for step s+1's buffer; end-of-step
// barrier uses COUNTED s_waitcnt vmcnt(5) (drains only the 2 DMA loads,
// leaves the 5 B-prefetch loads in flight). fp32->fp16 cvt on the
// fragment-read side. Rule-21 both-sides XOR swizzle (residual 8-way
// conflict is pigeonhole-forced at 128B row stride; ~128cy/step = 7%,
// not worth attacking). K-pad tail redirects to a zeroed block.
// LEDGER (R1-R11): direct-A loads, counted-vmcnt depth 2 AND 3, BK=64,
// 2x occupancy, fine phase-split+setprio, B single-buffer, cooperative
// gemm2+stat2+final fusion (grid.sync = ~350us, 100x too expensive) --
// all profiled-null or worse. Do not re-litigate without new evidence.

typedef const __attribute__((address_space(1))) void* gas_p;
typedef __attribute__((address_space(3))) void* las_p;

__device__ __forceinline__ void gload_lds16(const float* g, float* l)
{
    __builtin_amdgcn_global_load_lds((gas_p)g, (las_p)l, 16, 0, 0);
}

#define PF_B(BV, NK)                                                        \
    _Pragma("unroll")                                                       \
    for (int nt = 0; nt < 5; ++nt)                                          \
        BV[nt] = *(const half8*)(bb + (size_t)nt * 16 * KP + (NK));

#define ISSUE_A(BUF, KK)                                                    \
    gload_lds16(gA0 + (KK), &Afl[BUF][0][0] + lof);                         \
    gload_lds16(gA1 + (KK), &Afl[BUF][0][0] + 1024 + lof);

#define ISSUE_A_TAIL(BUF)                                                   \
    gload_lds16(ts0, &Afl[BUF][0][0] + lof);                                \
    gload_lds16(ts1, &Afl[BUF][0][0] + 1024 + lof);

// read swizzled chunks ce=(2q)^e, co=ce^1 of row mt*16+row15, cvt to half8
#define AFRAGF(BUF)                                                         \
    _Pragma("unroll")                                                       \
    for (int mt = 0; mt < 4; ++mt) {                                        \
        floatx4 f0 = *(const floatx4*)&Afl[BUF][mt * 16 + row15][ce * 4];   \
        floatx4 f1 = *(const floatx4*)&Afl[BUF][mt * 16 + row15][co * 4];   \
        half8 hv;                                                           \
        _Pragma("unroll")                                                   \
        for (int j = 0; j < 4; ++j) {                                       \
            hv[j]     = (_Float16)f0[j];                                    \
            hv[4 + j] = (_Float16)f1[j];                                    \
        }                                                                   \
        a[mt] = hv;                                                         \
    }

#define COMPUTE(BV)                                                         \
    _Pragma("unroll")                                                       \
    for (int nt = 0; nt < 5; ++nt)                                          \
        _Pragma("unroll")                                                   \
        for (int mt = 0; mt < 4; ++mt)                                      \
            acc[mt][nt] = __builtin_amdgcn_mfma_f32_16x16x32_f16(           \
                a[mt], BV[nt], acc[mt][nt], 0, 0, 0);

// counted drain: waits the 2 A-DMA loads (oldest), leaves 5 B loads in
// flight across the barrier. sched_barrier(0) pins issue order (rule 18).
#define STEP_SYNC()                                                         \
    __builtin_amdgcn_sched_barrier(0);                                      \
    asm volatile("s_waitcnt vmcnt(5)" ::: "memory");                        \
    __builtin_amdgcn_sched_barrier(0);                                      \
    __builtin_amdgcn_s_barrier();                                           \
    __builtin_amdgcn_sched_barrier(0);

__global__ __launch_bounds__(256) void k_gemm1(const float* __restrict__ x,
                                               const _Float16* __restrict__ S1,
                                               _Float16* __restrict__ h,
                                               float* __restrict__ part,
                                               const float* __restrict__ zb)
{
    __shared__ __align__(16) float Afl[2][64][32];   // 2 x 8 KB
    const int t     = threadIdx.x;
    const int wave  = t >> 6;
    const int lane  = t & 63;
    const int row15 = lane & 15;
    const int quad  = lane >> 4;
    const int m0    = blockIdx.x * 64;

    // DMA staging: slot = wave*64+lane (call0) / +256 (call1); row = slot>>3,
    // storage chunk = slot&7, source chunk = (slot&7)^(row&7).
    const int rA   = wave * 8 + (lane >> 3);          // call0 row (call1: +32)
    const int cswz = (lane & 7) ^ ((lane >> 3) & 7);  // swizzled source chunk
    const int lof  = wave * 256;                      // LDS float offset, call0
    const float* gA0 = x + (size_t)(m0 + rA) * D_IN + cswz * 4;
    const float* gA1 = gA0 + (size_t)32 * D_IN;
    // tail step (kk=768): cols 768+cswz*4 >= 784 for cswz>=4 -> zero block
    const float* ts0 = (cswz >= 4) ? zb : (gA0 + 768);
    const float* ts1 = (cswz >= 4) ? zb : (gA1 + 768);

    // fragment-read swizzle (e = row15&7 since (mt*16)&7 == 0)
    const int ce = (2 * quad) ^ (row15 & 7);
    const int co = ce ^ 1;

    // B fragment base (MFMA B layout: lane holds col=row15, k=quad*8..+8)
    const _Float16* bb = S1 + (size_t)(wave * 80 + row15) * KP + quad * 8;

    floatx4 acc[4][5] = {};
    half8   b0[5], b1[5];
    half8   a[4];

    // prologue: DMA A(0)->buf0; b0 <- B(0); counted drain; barrier
    ISSUE_A(0, 0)
    __builtin_amdgcn_sched_barrier(0);
    PF_B(b0, 0)
    STEP_SYNC()

    for (int i = 0; i < 12; ++i) {
        const int kk = i * 64;
        // even step s=2i: computes buf0/b0; DMA A(s+1)->buf1; prefetch b1
        ISSUE_A(1, kk + 32)
        __builtin_amdgcn_sched_barrier(0);
        PF_B(b1, kk + 32)
        AFRAGF(0)
        COMPUTE(b0)
        STEP_SYNC()
        // odd step s=2i+1: computes buf1/b1; DMA A(s+2)->buf0; prefetch b0
        if (i < 11) { ISSUE_A(0, kk + 64) } else { ISSUE_A_TAIL(0) }
        __builtin_amdgcn_sched_barrier(0);
        PF_B(b0, kk + 64)              // i=11 -> B(24) at koff 768
        AFRAGF(1)
        COMPUTE(b1)
        STEP_SYNC()
    }
    // tail step 24: buf0/b0 (k = 768..799; pad cols are zeros both sides)
    AFRAGF(0)
    COMPUTE(b0)

    // --- epilogue: store h (C/D layout: col=lane&15, row=quad*4+r) + stats
    float s[5] = {}, q[5] = {};
#pragma unroll
    for (int mt = 0; mt < 4; ++mt)
#pragma unroll
        for (int nt = 0; nt < 5; ++nt)
#pragma unroll
            for (int r = 0; r < 4; ++r) {
                float v = acc[mt][nt][r];
                int m = m0 + mt * 16 + quad * 4 + r;
                int n = wave * 80 + nt * 16 + row15;
                h[(size_t)m * NP + n] = (_Float16)v;
                s[nt] += v;
                q[nt] += v * v;
            }
    // reduce over quad (waves own disjoint col ranges -> no cross-wave combine)
#pragma unroll
    for (int nt = 0; nt < 5; ++nt) {
        s[nt] += __shfl_xor(s[nt], 16); s[nt] += __shfl_xor(s[nt], 32);
        q[nt] += __shfl_xor(q[nt], 16); q[nt] += __shfl_xor(q[nt], 32);
    }
    if (quad == 0) {
#pragma unroll
        for (int nt = 0; nt < 5; ++nt) {
            int col = wave * 80 + nt * 16 + row15;
            part[(size_t)col * NBLK + blockIdx.x]        = s[nt];
            part[(size_t)(NP + col) * NBLK + blockIdx.x] = q[nt];
        }
    }
}

// ---------------- K2: FUSED reduce + BN1-fold-into-W2
// One block per hidden col j: reduce sum AND sumsq partials, then threads
// 0..15 write the BN1-scaled binarized W2 column.
__global__ void k_stat1(const float* __restrict__ part, const float* __restrict__ gamma1,
                        const float* __restrict__ W2, _Float16* __restrict__ w2h)
{
    __shared__ float redS[4], redQ[4];
    const int j = blockIdx.x;            // 0..319
    const int t = threadIdx.x;           // 256
    const float* ps = part + (size_t)j * NBLK;
    const float* pq = part + (size_t)(NP + j) * NBLK;
    float s = ps[t] + ps[t + 256] + ps[t + 512] + ps[t + 768];
    float q = pq[t] + pq[t + 256] + pq[t + 512] + pq[t + 768];
#pragma unroll
    for (int off = 1; off < 64; off <<= 1) {
        s += __shfl_xor(s, off);
        q += __shfl_xor(q, off);
    }
    if ((t & 63) == 0) { redS[t >> 6] = s; redQ[t >> 6] = q; }
    __syncthreads();
    if (t < NP2) {
        float S = redS[0] + redS[1] + redS[2] + redS[3];
        float Q = redQ[0] + redQ[1] + redQ[2] + redQ[3];
        float mean = S * (1.0f / 65536.0f);
        float var  = Q * (1.0f / 65536.0f) - mean * mean;
        float a1   = 0.0f;
        if (j < D_H) a1 = gamma1[j] / sqrtf(var + EPS);
        float w = 0.0f;
        if (t < D_OUT && j < D_H)
            w = (W2[t * D_H + j] >= 0.0f) ? a1 : -a1;
        w2h[t * NP + j] = (_Float16)w;
    }
}

// ---------------- K3: oc = h @ w2h^T  (K=320, N=16) + per-block stat partials
__global__ __launch_bounds__(256) void k_gemm2(const _Float16* __restrict__ h,
                                               const _Float16* __restrict__ w2h,
                                               float* __restrict__ oc,
                                               float* __restrict__ part2)
{
    __shared__ _Float16 Wlds[16][328];   // pad 320->328 to break bank conflicts
    __shared__ float reds[4][16], redq[4][16];
    const int t     = threadIdx.x;
    const int wave  = t >> 6;
    const int lane  = t & 63;
    const int row15 = lane & 15;
    const int quad  = lane >> 4;

    for (int c = t; c < 640; c += 256) { // 16*320/8 chunks
        int r  = c / 40;
        int cc = (c - r * 40) * 8;
        *(half8*)&Wlds[r][cc] = *(const half8*)(w2h + r * NP + cc);
    }
    __syncthreads();

    const int m0 = blockIdx.x * 64 + wave * 16;
    const _Float16* hp = h + (size_t)(m0 + row15) * NP + quad * 8;
    floatx4 acc = {};
#pragma unroll
    for (int kk = 0; kk < NP; kk += 32) {
        half8 a2 = *(const half8*)(hp + kk);
        half8 b2 = *(const half8*)&Wlds[row15][kk + quad * 8];
        acc = __builtin_amdgcn_mfma_f32_16x16x32_f16(a2, b2, acc, 0, 0, 0);
    }
    float s = 0.f, q = 0.f;
#pragma unroll
    for (int r = 0; r < 4; ++r) {
        float v = acc[r];
        oc[(size_t)(m0 + quad * 4 + r) * NP2 + row15] = v;
        s += v; q += v * v;
    }
    s += __shfl_xor(s, 16); s += __shfl_xor(s, 32);
    q += __shfl_xor(q, 16); q += __shfl_xor(q, 32);
    if (lane < 16) { reds[wave][row15] = s; redq[wave][row15] = q; }
    __syncthreads();
    if (t < 16) {
        float S = reds[0][t] + reds[1][t] + reds[2][t] + reds[3][t];
        float Q = redq[0][t] + redq[1][t] + redq[2][t] + redq[3][t];
        part2[(size_t)t * NBLK + blockIdx.x]          = S;
        part2[(size_t)(16 + t) * NBLK + blockIdx.x]   = Q;
    }
}

// ---------------- K4: FUSED reduce#2 + BN2-coefficient precompute
__global__ void k_stat2(const float* __restrict__ part2, const float* __restrict__ gamma2,
                        float* __restrict__ st2)
{
    __shared__ float redS[4], redQ[4];
    const int k = blockIdx.x;            // 0..15
    const int t = threadIdx.x;           // 256
    const float* ps = part2 + (size_t)k * NBLK;
    const float* pq = part2 + (size_t)(16 + k) * NBLK;
    float s = ps[t] + ps[t + 256] + ps[t + 512] + ps[t + 768];
    float q = pq[t] + pq[t + 256] + pq[t + 512] + pq[t + 768];
#pragma unroll
    for (int off = 1; off < 64; off <<= 1) {
        s += __shfl_xor(s, off);
        q += __shfl_xor(q, off);
    }
    if ((t & 63) == 0) { redS[t >> 6] = s; redQ[t >> 6] = q; }
    __syncthreads();
    if (t == 0) {
        float S = redS[0] + redS[1] + redS[2] + redS[3];
        float Q = redQ[0] + redQ[1] + redQ[2] + redQ[3];
        float mean = S * (1.0f / 65536.0f);
        float var  = Q * (1.0f / 65536.0f) - mean * mean;
        float sc   = (k < D_OUT) ? gamma2[k] / sqrtf(var + EPS) : 0.0f;
        st2[k]      = mean;
        st2[16 + k] = sc;
    }
}

// ---------------- K5: BN2 epilogue -> out[65536][10] fp32
__global__ void k_final(const float* __restrict__ oc, const float* __restrict__ st2,
                        const float* __restrict__ beta2, float* __restrict__ out)
{
    int idx = blockIdx.x * 256 + threadIdx.x;    // 2560*256 == 655360 exactly
    int m = idx / 10;
    int k = idx - m * 10;
    float mean = st2[k];
    float sc   = st2[16 + k];
    out[idx] = (oc[(size_t)m * NP2 + k] - mean) * sc + beta2[k];
}

extern "C" void kernel_launch(void* const* d_in, const int* in_sizes, int n_in,
                              void* d_out, int out_size, void* d_ws, size_t ws_size,
                              hipStream_t stream)
{
    const float* x      = (const float*)d_in[0];
    const float* W1     = (const float*)d_in[1];
    const float* gamma1 = (const float*)d_in[2];
    // d_in[3] = beta1 : algebraically cancels under BN2's mean subtraction
    const float* W2     = (const float*)d_in[4];
    const float* gamma2 = (const float*)d_in[5];
    const float* beta2  = (const float*)d_in[6];
    float* out = (float*)d_out;

    char* ws = (char*)d_ws;
    _Float16* S1    = (_Float16*)(ws + OFF_S1);
    _Float16* h     = (_Float16*)(ws + OFF_H);
    float*    zb    = (float*)(ws + OFF_ZB);
    _Float16* w2h   = (_Float16*)(ws + OFF_W2);
    float*    st2   = (float*)(ws + OFF_ST2);
    float*    oc    = (float*)(ws + OFF_OC);
    float*    part  = (float*)(ws + OFF_P1);   // aliases oc (time-disjoint)
    float*    part2 = (float*)(ws + OFF_P2);

    k_prep1 <<<1000, 256, 0, stream>>>(W1, S1, zb);
    k_gemm1 <<<NBLK, 256, 0, stream>>>(x, S1, h, part, zb);
    k_stat1 <<<320, 256, 0, stream>>>(part, gamma1, W2, w2h);
    k_gemm2 <<<NBLK, 256, 0, stream>>>(h, w2h, oc, part2);
    k_stat2 <<<16, 256, 0, stream>>>(part2, gamma2, st2);
    k_final <<<2560, 256, 0, stream>>>(oc, st2, beta2, out);
}